// Round 20
// baseline (178.418 us; speedup 1.0000x reference)
//
#include <hip/hip_runtime.h>
#include <cstdint>
#include <cstddef>

typedef __bf16 bf16x8_t __attribute__((ext_vector_type(8)));
typedef float f32x4_t __attribute__((ext_vector_type(4)));

#define SCALE 0.3535533905932738f
#define LOG2E 1.4426950408889634f
#define NEG -1000000000.0f

__device__ __forceinline__ unsigned short f2b(float f) {
    unsigned int u = __builtin_bit_cast(unsigned int, f);
    u += 0x7FFFu + ((u >> 16) & 1u);   // round-to-nearest-even
    return (unsigned short)(u >> 16);
}

// swizzled LDS address (in shorts) for [*][64-short] tiles:
// logical (row, col) lives at row*64 + ((col/8) ^ (row&7))*8 + col%8
__device__ __forceinline__ int swz(int row, int chunk) {
    return row * 64 + (((chunk ^ (row & 7)) << 3));
}

// async global->LDS, 16B per lane; dest must be wave-uniform base (HW adds lane*16)
__device__ __forceinline__ void gld16(const void* g, void* l) {
    __builtin_amdgcn_global_load_lds(
        (const __attribute__((address_space(1))) unsigned int*)g,
        (__attribute__((address_space(3))) unsigned int*)l,
        16, 0, 0);
}

__device__ __forceinline__ unsigned int cvt_pk_bf16(float lo, float hi) {
    unsigned int r;
    asm("v_cvt_pk_bf16_f32 %0, %1, %2" : "=v"(r) : "v"(lo), "v"(hi));
    return r;
}

// ---------------- fp32 -> bf16 convert, 4 elems/thread ----------------
__global__ __launch_bounds__(256) void cvt_kernel(const float* __restrict__ in,
                                                  unsigned short* __restrict__ out,
                                                  int n4) {
    int i = blockIdx.x * 256 + threadIdx.x;
    if (i >= n4) return;
    const float4 f = reinterpret_cast<const float4*>(in)[i];
    ushort4 o;
    o.x = f2b(f.x); o.y = f2b(f.y); o.z = f2b(f.z); o.w = f2b(f.w);
    reinterpret_cast<ushort4*>(out)[i] = o;
}

// ---------------- GEMM1: qkv = A @ W^T + b, scatter to heads ----------------
// 2-phase pipeline; 512 threads / 8 waves on a 128x128 tile (each wave 32x64)
// -> 16 waves/CU at the same 64KB LDS (4 waves/SIMD latency hiding).
__global__ __launch_bounds__(512) void gemm_qkv(
    const unsigned short* __restrict__ A,
    const unsigned short* __restrict__ W,
    const float* __restrict__ bias,
    unsigned short* __restrict__ qb,   // [48][8][512][64], pre-scaled by SCALE*log2e
    unsigned short* __restrict__ kb,   // [48][8][512][64]
    unsigned short* __restrict__ vT)   // [48][8][64][512] (transposed)
{
    __shared__ unsigned short As[2][128*64];
    __shared__ unsigned short Bs[2][128*64];
    const int tid = threadIdx.x;
    const int lane = tid & 63;
    const int l15 = lane & 15, lhi = lane >> 4;
    const int wid = tid >> 6;                 // 0..7
    const int wr = wid >> 1, wc = wid & 1;    // wave -> 32-row, 64-col sub-tile
    // bijective XCD-chunked swizzle: nwg = 2304 = 8 * 288
    const int bid = blockIdx.x;
    const int sid = (bid & 7) * 288 + (bid >> 3);
    const int m0 = (sid / 12) * 128, n0 = (sid % 12) * 128;
    const int rA = lane >> 3;                 // row-within-8-row stripe
    const int sc = (lane & 7) ^ rA;           // pre-swizzled source chunk

    f32x4_t acc[2][4] = {};

#define QKV_STAGE(buf, k0)                                                         \
    do {                                                                           \
        _Pragma("unroll")                                                          \
        for (int j = 0; j < 2; ++j) {                                              \
            const int ch = 2*wid + j;                                              \
            const int gr = ch*8 + rA;                                              \
            gld16(&A[(size_t)(m0+gr)*512 + (k0) + sc*8], &As[buf][ch*512]);        \
            gld16(&W[(size_t)(n0+gr)*512 + (k0) + sc*8], &Bs[buf][ch*512]);        \
        }                                                                          \
    } while (0)

    QKV_STAGE(0, 0);
    asm volatile("s_waitcnt vmcnt(0)" ::: "memory");
    __syncthreads();

    int cur = 0;
#pragma unroll
    for (int t = 0; t < 8; ++t) {
        if (t < 7) QKV_STAGE(cur ^ 1, (t+1)*64);   // prefetch next tile (no wait)
#pragma unroll
        for (int kk = 0; kk < 2; ++kk) {
            bf16x8_t af[2], bfr[4];
#pragma unroll
            for (int x = 0; x < 2; ++x)
                af[x]  = *reinterpret_cast<const bf16x8_t*>(&As[cur][swz(wr*32 + x*16 + l15, kk*4 + lhi)]);
#pragma unroll
            for (int x = 0; x < 4; ++x)
                bfr[x] = *reinterpret_cast<const bf16x8_t*>(&Bs[cur][swz(wc*64 + x*16 + l15, kk*4 + lhi)]);
            __builtin_amdgcn_s_setprio(1);
#pragma unroll
            for (int mi = 0; mi < 2; ++mi)
#pragma unroll
                for (int nj = 0; nj < 4; ++nj)
                    acc[mi][nj] = __builtin_amdgcn_mfma_f32_16x16x32_bf16(af[mi], bfr[nj], acc[mi][nj], 0, 0, 0);
            __builtin_amdgcn_s_setprio(0);
        }
        if (t < 7) {
            asm volatile("s_waitcnt vmcnt(0)" ::: "memory");  // next tile landed (mostly hidden)
            __syncthreads();                                   // everyone done with buf[cur]
            cur ^= 1;
        }
    }
#undef QKV_STAGE

#pragma unroll
    for (int mi = 0; mi < 2; ++mi) {
#pragma unroll
        for (int nj = 0; nj < 4; ++nj) {
            const int gn = n0 + wc*64 + nj*16 + l15;
            const float bi = bias[gn];
            const int which = gn >> 9, hh = (gn >> 6) & 7, dh = gn & 63;
#pragma unroll
            for (int i = 0; i < 4; ++i) {
                const int gm = m0 + wr*32 + mi*16 + lhi*4 + i;
                const int bt = gm >> 9, row = gm & 511;
                const float v = acc[mi][nj][i] + bi;
                const size_t ho = (size_t)bt*8 + hh;
                if (which == 0)      qb[ho*(512*64) + (size_t)row*64 + dh] = f2b(v * (SCALE * LOG2E));
                else if (which == 1) kb[ho*(512*64) + (size_t)row*64 + dh] = f2b(v);
                else                 vT[ho*(64*512) + (size_t)dh*512 + row] = f2b(v);
            }
        }
    }
}

// ---------------- fused masked attention: fixed-max, half-telescoped, single-barrier ----------------
// (exact Round-17 source: library exp2f, two uint Ps stores, runtime kbk loop)
__global__ __launch_bounds__(512, 4) void attn_kernel(
    const unsigned short* __restrict__ qb,
    const unsigned short* __restrict__ kb,
    const unsigned short* __restrict__ vT,
    const int* __restrict__ Mm,
    unsigned short* __restrict__ ob)   // [24576][512] bf16
{
    __shared__ unsigned short Ks[2][64*64];
    __shared__ unsigned short Vs[2][64*64];   // [dh][k], swizzled
    __shared__ unsigned short Ps[8][32*40];   // per-wave P half-tile [32q][32k + 8 pad]

    const int tid = threadIdx.x;
    const int lane = tid & 63;
    const int w = tid >> 6;
    const int l15 = lane & 15, lhi = lane >> 4;
    // XCD-chunked flat grid (768 = 8*96): qt pairs of same (h,bt) stay on one XCD
    const int bid = blockIdx.x;
    const int sid = (bid & 7) * 96 + (bid >> 3);
    const int qt = sid & 1;
    const int h  = (sid >> 1) & 7;
    const int bt = sid >> 4;
    const int q0 = qt*256 + w*32;
    const size_t hoQK = ((size_t)bt*8 + h) * (512*64);
    const size_t hoV  = ((size_t)bt*8 + h) * (64*512);

    const int rA = lane >> 3;
    const int sc = (lane & 7) ^ rA;           // pre-swizzled source chunk
    const int trK = w*8 + rA;                 // K tile row this wave stages (chunk w)

    // Q fragments: B-operand for S^T = K·Q^T
    bf16x8_t qf[2][2];
#pragma unroll
    for (int qmi = 0; qmi < 2; ++qmi)
#pragma unroll
        for (int kk = 0; kk < 2; ++kk)
            qf[qmi][kk] = *reinterpret_cast<const bf16x8_t*>(
                &qb[hoQK + (size_t)(q0 + qmi*16 + l15)*64 + kk*32 + lhi*8]);

    bf16x8_t ones;
    {
        uint4 u = {0x3F803F80u, 0x3F803F80u, 0x3F803F80u, 0x3F803F80u};
        ones = __builtin_bit_cast(bf16x8_t, u);
    }

    f32x4_t of[2][4] = {};
    f32x4_t ofl[2] = {};

    const size_t mrow0 = ((size_t)bt*512 + q0 + l15) * 512;  // + qmi*16*512 + k

    // prologue: stage tile 0 into buf 0 (each wave: 1 K chunk + 1 V chunk)
    gld16(&kb[hoQK + (size_t)trK*64 + sc*8],          &Ks[0][w*512]);
    gld16(&vT[hoV + (size_t)(w*8 + rA)*512 + sc*8],   &Vs[0][w*512]);
    asm volatile("s_waitcnt vmcnt(0)" ::: "memory");
    __syncthreads();

    for (int kbk = 0; kbk < 8; ++kbk) {
        const int cur = kbk & 1;
        // ---- issue next tile's K/V prefetch before computing this tile
        if (kbk < 7) {
            const int t = kbk + 1, nb = cur ^ 1;
            gld16(&kb[hoQK + (size_t)(t*64 + trK)*64 + sc*8],        &Ks[nb][w*512]);
            gld16(&vT[hoV + (size_t)(w*8 + rA)*512 + t*64 + sc*8],   &Vs[nb][w*512]);
        }

        // ---- process this K-tile in two knj-halves (transient regs telescope)
#pragma unroll
        for (int half = 0; half < 2; ++half) {
            // K fragments for this half: knj = half*2 + knjh
            bf16x8_t kf[2][2];
#pragma unroll
            for (int knjh = 0; knjh < 2; ++knjh)
#pragma unroll
                for (int kk = 0; kk < 2; ++kk)
                    kf[knjh][kk] = *reinterpret_cast<const bf16x8_t*>(
                        &Ks[cur][swz((half*2 + knjh)*16 + l15, kk*4 + lhi)]);

            // mask loads for this half (consumed right after QK^T)
            int4 mv[2][2];
#pragma unroll
            for (int knjh = 0; knjh < 2; ++knjh)
#pragma unroll
                for (int qmi = 0; qmi < 2; ++qmi)
                    mv[knjh][qmi] = *reinterpret_cast<const int4*>(
                        &Mm[mrow0 + (size_t)(qmi*16)*512 + kbk*64 + (half*2 + knjh)*16 + lhi*4]);

            // S^T for this half: sa[knjh][qmi]
            f32x4_t sa[2][2] = {};
            __builtin_amdgcn_s_setprio(1);
#pragma unroll
            for (int kk = 0; kk < 2; ++kk)
#pragma unroll
                for (int knjh = 0; knjh < 2; ++knjh)
#pragma unroll
                    for (int qmi = 0; qmi < 2; ++qmi)
                        sa[knjh][qmi] = __builtin_amdgcn_mfma_f32_16x16x32_bf16(
                            kf[knjh][kk], qf[qmi][kk], sa[knjh][qmi], 0, 0, 0);
            __builtin_amdgcn_s_setprio(0);

            // mask + exp2 + pack -> Ps (fixed-max; masked -> exp2(-1e9) == 0)
#pragma unroll
            for (int knjh = 0; knjh < 2; ++knjh)
#pragma unroll
                for (int qmi = 0; qmi < 2; ++qmi) {
                    const float p0 = exp2f(fmaf((float)mv[knjh][qmi].x, NEG, sa[knjh][qmi][0]));
                    const float p1 = exp2f(fmaf((float)mv[knjh][qmi].y, NEG, sa[knjh][qmi][1]));
                    const float p2 = exp2f(fmaf((float)mv[knjh][qmi].z, NEG, sa[knjh][qmi][2]));
                    const float p3 = exp2f(fmaf((float)mv[knjh][qmi].w, NEG, sa[knjh][qmi][3]));
                    const unsigned int p01 = cvt_pk_bf16(p0, p1);
                    const unsigned int p23 = cvt_pk_bf16(p2, p3);
                    const int base = (qmi*16 + l15)*40 + knjh*16 + lhi*4;
                    *reinterpret_cast<unsigned int*>(&Ps[w][base])     = p01;
                    *reinterpret_cast<unsigned int*>(&Ps[w][base + 2]) = p23;
                }

            // PV for this half
            bf16x8_t pf[2];
#pragma unroll
            for (int qmi = 0; qmi < 2; ++qmi)
                pf[qmi] = *reinterpret_cast<const bf16x8_t*>(&Ps[w][(qmi*16 + l15)*40 + lhi*8]);

            bf16x8_t vf[4];
#pragma unroll
            for (int dj = 0; dj < 4; ++dj)
                vf[dj] = *reinterpret_cast<const bf16x8_t*>(&Vs[cur][swz(dj*16 + l15, half*4 + lhi)]);

            __builtin_amdgcn_s_setprio(1);
#pragma unroll
            for (int qmi = 0; qmi < 2; ++qmi) {
                ofl[qmi] = __builtin_amdgcn_mfma_f32_16x16x32_bf16(pf[qmi], ones, ofl[qmi], 0, 0, 0);
#pragma unroll
                for (int dj = 0; dj < 4; ++dj)
                    of[qmi][dj] = __builtin_amdgcn_mfma_f32_16x16x32_bf16(pf[qmi], vf[dj], of[qmi][dj], 0, 0, 0);
            }
            __builtin_amdgcn_s_setprio(0);
        }

        // ---- single barrier per tile: prefetch landed (hidden under compute)
        //      + everyone done reading buf[cur]
        if (kbk < 7) {
            asm volatile("s_waitcnt vmcnt(0)" ::: "memory");
            __syncthreads();
        }
    }

    // ---- epilogue: normalize by l (same C-layout as of)
#pragma unroll
    for (int qmi = 0; qmi < 2; ++qmi)
#pragma unroll
        for (int i = 0; i < 4; ++i) {
            const int qrow = q0 + qmi*16 + lhi*4 + i;
            const float inv = 1.f / ofl[qmi][i];
#pragma unroll
            for (int dj = 0; dj < 4; ++dj)
                ob[((size_t)bt*512 + qrow)*512 + h*64 + dj*16 + l15] = f2b(of[qmi][dj][i] * inv);
        }
}

// ---------------- GEMM2: out = A @ Wo^T + b (fp32 out), 2-phase, 8 waves ----------------
__global__ __launch_bounds__(512) void gemm_out(
    const unsigned short* __restrict__ A,   // [24576][512] bf16
    const unsigned short* __restrict__ W,   // [512][512] bf16
    const float* __restrict__ bias,
    float* __restrict__ out)
{
    __shared__ unsigned short As[2][128*64];
    __shared__ unsigned short Bs[2][128*64];
    const int tid = threadIdx.x;
    const int lane = tid & 63;
    const int l15 = lane & 15, lhi = lane >> 4;
    const int wid = tid >> 6;                 // 0..7
    const int wr = wid >> 1, wc = wid & 1;
    // bijective XCD-chunked swizzle: nwg = 768 = 8 * 96
    const int bid = blockIdx.x;
    const int sid = (bid & 7) * 96 + (bid >> 3);
    const int m0 = (sid / 4) * 128, n0 = (sid % 4) * 128;
    const int rA = lane >> 3;
    const int sc = (lane & 7) ^ rA;

    f32x4_t acc[2][4] = {};

#define OUT_STAGE(buf, k0)                                                         \
    do {                                                                           \
        _Pragma("unroll")                                                          \
        for (int j = 0; j < 2; ++j) {                                              \
            const int ch = 2*wid + j;                                              \
            const int gr = ch*8 + rA;                                              \
            gld16(&A[(size_t)(m0+gr)*512 + (k0) + sc*8], &As[buf][ch*512]);        \
            gld16(&W[(size_t)(n0+gr)*512 + (k0) + sc*8], &Bs[buf][ch*512]);        \
        }                                                                          \
    } while (0)

    OUT_STAGE(0, 0);
    asm volatile("s_waitcnt vmcnt(0)" ::: "memory");
    __syncthreads();

    int cur = 0;
#pragma unroll
    for (int t = 0; t < 8; ++t) {
        if (t < 7) OUT_STAGE(cur ^ 1, (t+1)*64);
#pragma unroll
        for (int kk = 0; kk < 2; ++kk) {
            bf16x8_t af[2], bfr[4];
#pragma unroll
            for (int x = 0; x < 2; ++x)
                af[x]  = *reinterpret_cast<const bf16x8_t*>(&As[cur][swz(wr*32 + x*16 + l15, kk*4 + lhi)]);
#pragma unroll
            for (int x = 0; x < 4; ++x)
                bfr[x] = *reinterpret_cast<const bf16x8_t*>(&Bs[cur][swz(wc*64 + x*16 + l15, kk*4 + lhi)]);
            __builtin_amdgcn_s_setprio(1);
#pragma unroll
            for (int mi = 0; mi < 2; ++mi)
#pragma unroll
                for (int nj = 0; nj < 4; ++nj)
                    acc[mi][nj] = __builtin_amdgcn_mfma_f32_16x16x32_bf16(af[mi], bfr[nj], acc[mi][nj], 0, 0, 0);
            __builtin_amdgcn_s_setprio(0);
        }
        if (t < 7) {
            asm volatile("s_waitcnt vmcnt(0)" ::: "memory");
            __syncthreads();
            cur ^= 1;
        }
    }
#undef OUT_STAGE

#pragma unroll
    for (int mi = 0; mi < 2; ++mi) {
#pragma unroll
        for (int nj = 0; nj < 4; ++nj) {
            const int gn = n0 + wc*64 + nj*16 + l15;
            const float bi = bias[gn];
#pragma unroll
            for (int i = 0; i < 4; ++i) {
                const int gm = m0 + wr*32 + mi*16 + lhi*4 + i;
                out[(size_t)gm*512 + gn] = acc[mi][nj][i] + bi;
            }
        }
    }
}

extern "C" void kernel_launch(void* const* d_in, const int* in_sizes, int n_in,
                              void* d_out, int out_size, void* d_ws, size_t ws_size,
                              hipStream_t stream) {
    (void)in_sizes; (void)n_in; (void)out_size; (void)ws_size;
    // setup_inputs order: V, K, Q, M, wx_w, wx_b, wo_w, wo_b  (V,K unused by reference)
    const float* Qin = (const float*)d_in[2];
    const int*   Mm  = (const int*)d_in[3];
    const float* wxw = (const float*)d_in[4];
    const float* wxb = (const float*)d_in[5];
    const float* wow = (const float*)d_in[6];
    const float* wob = (const float*)d_in[7];
    float* out = (float*)d_out;

    char* ws = (char*)d_ws;
    const size_t SZ_A  = (size_t)24576*512*2;   // Q bf16 / attn-out bf16 (reused)
    const size_t SZ_WX = (size_t)1536*512*2;
    const size_t SZ_WO = (size_t)512*512*2;
    const size_t SZ_H  = (size_t)48*8*512*64*2; // per q/k/vT buffer

    unsigned short* Abf  = (unsigned short*)(ws);
    unsigned short* Wxb  = (unsigned short*)(ws + SZ_A);
    unsigned short* Wob  = (unsigned short*)(ws + SZ_A + SZ_WX);
    unsigned short* qb   = (unsigned short*)(ws + SZ_A + SZ_WX + SZ_WO);
    unsigned short* kbuf = (unsigned short*)(ws + SZ_A + SZ_WX + SZ_WO + SZ_H);
    unsigned short* vT   = (unsigned short*)(ws + SZ_A + SZ_WX + SZ_WO + 2*SZ_H);
    unsigned short* attn = Abf;  // reuse: GEMM1 is done with Abf before attention writes

    cvt_kernel<<<(24576*512/4)/256, 256, 0, stream>>>(Qin, Abf, 24576*512/4);
    cvt_kernel<<<(1536*512/4)/256, 256, 0, stream>>>(wxw, Wxb, 1536*512/4);
    cvt_kernel<<<(512*512/4)/256, 256, 0, stream>>>(wow, Wob, 512*512/4);

    gemm_qkv<<<2304, 512, 0, stream>>>(Abf, Wxb, wxb, qb, kbuf, vT);
    attn_kernel<<<768, 512, 0, stream>>>(qb, kbuf, vT, Mm, attn);
    gemm_out<<<768, 512, 0, stream>>>(attn, Wob, wob, out);
}

// Round 21
// 175.689 us; speedup vs baseline: 1.0155x; 1.0155x over previous
//
#include <hip/hip_runtime.h>
#include <cstdint>
#include <cstddef>

typedef __bf16 bf16x8_t __attribute__((ext_vector_type(8)));
typedef float f32x4_t __attribute__((ext_vector_type(4)));

#define SCALE 0.3535533905932738f
#define LOG2E 1.4426950408889634f
#define NEG -1000000000.0f

__device__ __forceinline__ unsigned short f2b(float f) {
    unsigned int u = __builtin_bit_cast(unsigned int, f);
    u += 0x7FFFu + ((u >> 16) & 1u);   // round-to-nearest-even
    return (unsigned short)(u >> 16);
}

// swizzled LDS address (in shorts) for [*][64-short] tiles:
// logical (row, col) lives at row*64 + ((col/8) ^ (row&7))*8 + col%8
__device__ __forceinline__ int swz(int row, int chunk) {
    return row * 64 + (((chunk ^ (row & 7)) << 3));
}

// async global->LDS, 16B per lane; dest must be wave-uniform base (HW adds lane*16)
__device__ __forceinline__ void gld16(const void* g, void* l) {
    __builtin_amdgcn_global_load_lds(
        (const __attribute__((address_space(1))) unsigned int*)g,
        (__attribute__((address_space(3))) unsigned int*)l,
        16, 0, 0);
}

__device__ __forceinline__ unsigned int cvt_pk_bf16(float lo, float hi) {
    unsigned int r;
    asm("v_cvt_pk_bf16_f32 %0, %1, %2" : "=v"(r) : "v"(lo), "v"(hi));
    return r;
}

// ---------------- fused fp32 -> bf16 convert for Q, wx_w, wo_w (one launch) ----------------
__global__ __launch_bounds__(256) void cvt_all(const float* __restrict__ Qin,
                                               const float* __restrict__ wxw,
                                               const float* __restrict__ wow,
                                               unsigned short* __restrict__ oQ,
                                               unsigned short* __restrict__ owx,
                                               unsigned short* __restrict__ owo) {
    const int nQ  = 24576*512/4;
    const int nWX = 1536*512/4;
    const int nWO = 512*512/4;
    int i = blockIdx.x * 256 + threadIdx.x;
    const float* in; unsigned short* out;
    if (i < nQ)            { in = Qin; out = oQ; }
    else if (i < nQ+nWX)   { i -= nQ;  in = wxw; out = owx; }
    else if (i < nQ+nWX+nWO) { i -= nQ+nWX; in = wow; out = owo; }
    else return;
    const float4 f = reinterpret_cast<const float4*>(in)[i];
    ushort4 o;
    o.x = f2b(f.x); o.y = f2b(f.y); o.z = f2b(f.z); o.w = f2b(f.w);
    reinterpret_cast<ushort4*>(out)[i] = o;
}

// ---------------- GEMM1: qkv = A @ W^T + b, scatter to heads ----------------
// 2-phase pipeline; 512 threads / 8 waves on a 128x128 tile (each wave 32x64)
// -> 16 waves/CU at the same 64KB LDS (4 waves/SIMD latency hiding).
__global__ __launch_bounds__(512) void gemm_qkv(
    const unsigned short* __restrict__ A,
    const unsigned short* __restrict__ W,
    const float* __restrict__ bias,
    unsigned short* __restrict__ qb,   // [48][8][512][64], pre-scaled by SCALE*log2e
    unsigned short* __restrict__ kb,   // [48][8][512][64]
    unsigned short* __restrict__ vT)   // [48][8][64][512] (transposed)
{
    __shared__ unsigned short As[2][128*64];
    __shared__ unsigned short Bs[2][128*64];
    const int tid = threadIdx.x;
    const int lane = tid & 63;
    const int l15 = lane & 15, lhi = lane >> 4;
    const int wid = tid >> 6;                 // 0..7
    const int wr = wid >> 1, wc = wid & 1;    // wave -> 32-row, 64-col sub-tile
    // bijective XCD-chunked swizzle: nwg = 2304 = 8 * 288
    const int bid = blockIdx.x;
    const int sid = (bid & 7) * 288 + (bid >> 3);
    const int m0 = (sid / 12) * 128, n0 = (sid % 12) * 128;
    const int rA = lane >> 3;                 // row-within-8-row stripe
    const int sc = (lane & 7) ^ rA;           // pre-swizzled source chunk

    f32x4_t acc[2][4] = {};

#define QKV_STAGE(buf, k0)                                                         \
    do {                                                                           \
        _Pragma("unroll")                                                          \
        for (int j = 0; j < 2; ++j) {                                              \
            const int ch = 2*wid + j;                                              \
            const int gr = ch*8 + rA;                                              \
            gld16(&A[(size_t)(m0+gr)*512 + (k0) + sc*8], &As[buf][ch*512]);        \
            gld16(&W[(size_t)(n0+gr)*512 + (k0) + sc*8], &Bs[buf][ch*512]);        \
        }                                                                          \
    } while (0)

    QKV_STAGE(0, 0);
    asm volatile("s_waitcnt vmcnt(0)" ::: "memory");
    __syncthreads();

    int cur = 0;
#pragma unroll
    for (int t = 0; t < 8; ++t) {
        if (t < 7) QKV_STAGE(cur ^ 1, (t+1)*64);   // prefetch next tile (no wait)
#pragma unroll
        for (int kk = 0; kk < 2; ++kk) {
            bf16x8_t af[2], bfr[4];
#pragma unroll
            for (int x = 0; x < 2; ++x)
                af[x]  = *reinterpret_cast<const bf16x8_t*>(&As[cur][swz(wr*32 + x*16 + l15, kk*4 + lhi)]);
#pragma unroll
            for (int x = 0; x < 4; ++x)
                bfr[x] = *reinterpret_cast<const bf16x8_t*>(&Bs[cur][swz(wc*64 + x*16 + l15, kk*4 + lhi)]);
            __builtin_amdgcn_s_setprio(1);
#pragma unroll
            for (int mi = 0; mi < 2; ++mi)
#pragma unroll
                for (int nj = 0; nj < 4; ++nj)
                    acc[mi][nj] = __builtin_amdgcn_mfma_f32_16x16x32_bf16(af[mi], bfr[nj], acc[mi][nj], 0, 0, 0);
            __builtin_amdgcn_s_setprio(0);
        }
        if (t < 7) {
            asm volatile("s_waitcnt vmcnt(0)" ::: "memory");  // next tile landed (mostly hidden)
            __syncthreads();                                   // everyone done with buf[cur]
            cur ^= 1;
        }
    }
#undef QKV_STAGE

#pragma unroll
    for (int mi = 0; mi < 2; ++mi) {
#pragma unroll
        for (int nj = 0; nj < 4; ++nj) {
            const int gn = n0 + wc*64 + nj*16 + l15;
            const float bi = bias[gn];
            const int which = gn >> 9, hh = (gn >> 6) & 7, dh = gn & 63;
#pragma unroll
            for (int i = 0; i < 4; ++i) {
                const int gm = m0 + wr*32 + mi*16 + lhi*4 + i;
                const int bt = gm >> 9, row = gm & 511;
                const float v = acc[mi][nj][i] + bi;
                const size_t ho = (size_t)bt*8 + hh;
                if (which == 0)      qb[ho*(512*64) + (size_t)row*64 + dh] = f2b(v * (SCALE * LOG2E));
                else if (which == 1) kb[ho*(512*64) + (size_t)row*64 + dh] = f2b(v);
                else                 vT[ho*(64*512) + (size_t)dh*512 + row] = f2b(v);
            }
        }
    }
}

// ---------------- fused masked attention: fixed-max, half-telescoped, single-barrier ----------------
// (exact Round-17/20 source: library exp2f, two uint Ps stores, runtime kbk loop)
__global__ __launch_bounds__(512, 4) void attn_kernel(
    const unsigned short* __restrict__ qb,
    const unsigned short* __restrict__ kb,
    const unsigned short* __restrict__ vT,
    const int* __restrict__ Mm,
    unsigned short* __restrict__ ob)   // [24576][512] bf16
{
    __shared__ unsigned short Ks[2][64*64];
    __shared__ unsigned short Vs[2][64*64];   // [dh][k], swizzled
    __shared__ unsigned short Ps[8][32*40];   // per-wave P half-tile [32q][32k + 8 pad]

    const int tid = threadIdx.x;
    const int lane = tid & 63;
    const int w = tid >> 6;
    const int l15 = lane & 15, lhi = lane >> 4;
    // XCD-chunked flat grid (768 = 8*96): qt pairs of same (h,bt) stay on one XCD
    const int bid = blockIdx.x;
    const int sid = (bid & 7) * 96 + (bid >> 3);
    const int qt = sid & 1;
    const int h  = (sid >> 1) & 7;
    const int bt = sid >> 4;
    const int q0 = qt*256 + w*32;
    const size_t hoQK = ((size_t)bt*8 + h) * (512*64);
    const size_t hoV  = ((size_t)bt*8 + h) * (64*512);

    const int rA = lane >> 3;
    const int sc = (lane & 7) ^ rA;           // pre-swizzled source chunk
    const int trK = w*8 + rA;                 // K tile row this wave stages (chunk w)

    // Q fragments: B-operand for S^T = K·Q^T
    bf16x8_t qf[2][2];
#pragma unroll
    for (int qmi = 0; qmi < 2; ++qmi)
#pragma unroll
        for (int kk = 0; kk < 2; ++kk)
            qf[qmi][kk] = *reinterpret_cast<const bf16x8_t*>(
                &qb[hoQK + (size_t)(q0 + qmi*16 + l15)*64 + kk*32 + lhi*8]);

    bf16x8_t ones;
    {
        uint4 u = {0x3F803F80u, 0x3F803F80u, 0x3F803F80u, 0x3F803F80u};
        ones = __builtin_bit_cast(bf16x8_t, u);
    }

    f32x4_t of[2][4] = {};
    f32x4_t ofl[2] = {};

    const size_t mrow0 = ((size_t)bt*512 + q0 + l15) * 512;  // + qmi*16*512 + k

    // prologue: stage tile 0 into buf 0 (each wave: 1 K chunk + 1 V chunk)
    gld16(&kb[hoQK + (size_t)trK*64 + sc*8],          &Ks[0][w*512]);
    gld16(&vT[hoV + (size_t)(w*8 + rA)*512 + sc*8],   &Vs[0][w*512]);
    asm volatile("s_waitcnt vmcnt(0)" ::: "memory");
    __syncthreads();

    for (int kbk = 0; kbk < 8; ++kbk) {
        const int cur = kbk & 1;
        // ---- issue next tile's K/V prefetch before computing this tile
        if (kbk < 7) {
            const int t = kbk + 1, nb = cur ^ 1;
            gld16(&kb[hoQK + (size_t)(t*64 + trK)*64 + sc*8],        &Ks[nb][w*512]);
            gld16(&vT[hoV + (size_t)(w*8 + rA)*512 + t*64 + sc*8],   &Vs[nb][w*512]);
        }

        // ---- process this K-tile in two knj-halves (transient regs telescope)
#pragma unroll
        for (int half = 0; half < 2; ++half) {
            // K fragments for this half: knj = half*2 + knjh
            bf16x8_t kf[2][2];
#pragma unroll
            for (int knjh = 0; knjh < 2; ++knjh)
#pragma unroll
                for (int kk = 0; kk < 2; ++kk)
                    kf[knjh][kk] = *reinterpret_cast<const bf16x8_t*>(
                        &Ks[cur][swz((half*2 + knjh)*16 + l15, kk*4 + lhi)]);

            // mask loads for this half (consumed right after QK^T)
            int4 mv[2][2];
#pragma unroll
            for (int knjh = 0; knjh < 2; ++knjh)
#pragma unroll
                for (int qmi = 0; qmi < 2; ++qmi)
                    mv[knjh][qmi] = *reinterpret_cast<const int4*>(
                        &Mm[mrow0 + (size_t)(qmi*16)*512 + kbk*64 + (half*2 + knjh)*16 + lhi*4]);

            // S^T for this half: sa[knjh][qmi]
            f32x4_t sa[2][2] = {};
            __builtin_amdgcn_s_setprio(1);
#pragma unroll
            for (int kk = 0; kk < 2; ++kk)
#pragma unroll
                for (int knjh = 0; knjh < 2; ++knjh)
#pragma unroll
                    for (int qmi = 0; qmi < 2; ++qmi)
                        sa[knjh][qmi] = __builtin_amdgcn_mfma_f32_16x16x32_bf16(
                            kf[knjh][kk], qf[qmi][kk], sa[knjh][qmi], 0, 0, 0);
            __builtin_amdgcn_s_setprio(0);

            // mask + exp2 + pack -> Ps (fixed-max; masked -> exp2(-1e9) == 0)
#pragma unroll
            for (int knjh = 0; knjh < 2; ++knjh)
#pragma unroll
                for (int qmi = 0; qmi < 2; ++qmi) {
                    const float p0 = exp2f(fmaf((float)mv[knjh][qmi].x, NEG, sa[knjh][qmi][0]));
                    const float p1 = exp2f(fmaf((float)mv[knjh][qmi].y, NEG, sa[knjh][qmi][1]));
                    const float p2 = exp2f(fmaf((float)mv[knjh][qmi].z, NEG, sa[knjh][qmi][2]));
                    const float p3 = exp2f(fmaf((float)mv[knjh][qmi].w, NEG, sa[knjh][qmi][3]));
                    const unsigned int p01 = cvt_pk_bf16(p0, p1);
                    const unsigned int p23 = cvt_pk_bf16(p2, p3);
                    const int base = (qmi*16 + l15)*40 + knjh*16 + lhi*4;
                    *reinterpret_cast<unsigned int*>(&Ps[w][base])     = p01;
                    *reinterpret_cast<unsigned int*>(&Ps[w][base + 2]) = p23;
                }

            // PV for this half
            bf16x8_t pf[2];
#pragma unroll
            for (int qmi = 0; qmi < 2; ++qmi)
                pf[qmi] = *reinterpret_cast<const bf16x8_t*>(&Ps[w][(qmi*16 + l15)*40 + lhi*8]);

            bf16x8_t vf[4];
#pragma unroll
            for (int dj = 0; dj < 4; ++dj)
                vf[dj] = *reinterpret_cast<const bf16x8_t*>(&Vs[cur][swz(dj*16 + l15, half*4 + lhi)]);

            __builtin_amdgcn_s_setprio(1);
#pragma unroll
            for (int qmi = 0; qmi < 2; ++qmi) {
                ofl[qmi] = __builtin_amdgcn_mfma_f32_16x16x32_bf16(pf[qmi], ones, ofl[qmi], 0, 0, 0);
#pragma unroll
                for (int dj = 0; dj < 4; ++dj)
                    of[qmi][dj] = __builtin_amdgcn_mfma_f32_16x16x32_bf16(pf[qmi], vf[dj], of[qmi][dj], 0, 0, 0);
            }
            __builtin_amdgcn_s_setprio(0);
        }

        // ---- single barrier per tile: prefetch landed (hidden under compute)
        //      + everyone done reading buf[cur]
        if (kbk < 7) {
            asm volatile("s_waitcnt vmcnt(0)" ::: "memory");
            __syncthreads();
        }
    }

    // ---- epilogue: normalize by l (same C-layout as of)
#pragma unroll
    for (int qmi = 0; qmi < 2; ++qmi)
#pragma unroll
        for (int i = 0; i < 4; ++i) {
            const int qrow = q0 + qmi*16 + lhi*4 + i;
            const float inv = 1.f / ofl[qmi][i];
#pragma unroll
            for (int dj = 0; dj < 4; ++dj)
                ob[((size_t)bt*512 + qrow)*512 + h*64 + dj*16 + l15] = f2b(of[qmi][dj][i] * inv);
        }
}

// ---------------- GEMM2: out = A @ Wo^T + b (fp32 out), 2-phase, 8 waves ----------------
__global__ __launch_bounds__(512) void gemm_out(
    const unsigned short* __restrict__ A,   // [24576][512] bf16
    const unsigned short* __restrict__ W,   // [512][512] bf16
    const float* __restrict__ bias,
    float* __restrict__ out)
{
    __shared__ unsigned short As[2][128*64];
    __shared__ unsigned short Bs[2][128*64];
    const int tid = threadIdx.x;
    const int lane = tid & 63;
    const int l15 = lane & 15, lhi = lane >> 4;
    const int wid = tid >> 6;                 // 0..7
    const int wr = wid >> 1, wc = wid & 1;
    // bijective XCD-chunked swizzle: nwg = 768 = 8 * 96
    const int bid = blockIdx.x;
    const int sid = (bid & 7) * 96 + (bid >> 3);
    const int m0 = (sid / 4) * 128, n0 = (sid % 4) * 128;
    const int rA = lane >> 3;
    const int sc = (lane & 7) ^ rA;

    f32x4_t acc[2][4] = {};

#define OUT_STAGE(buf, k0)                                                         \
    do {                                                                           \
        _Pragma("unroll")                                                          \
        for (int j = 0; j < 2; ++j) {                                              \
            const int ch = 2*wid + j;                                              \
            const int gr = ch*8 + rA;                                              \
            gld16(&A[(size_t)(m0+gr)*512 + (k0) + sc*8], &As[buf][ch*512]);        \
            gld16(&W[(size_t)(n0+gr)*512 + (k0) + sc*8], &Bs[buf][ch*512]);        \
        }                                                                          \
    } while (0)

    OUT_STAGE(0, 0);
    asm volatile("s_waitcnt vmcnt(0)" ::: "memory");
    __syncthreads();

    int cur = 0;
#pragma unroll
    for (int t = 0; t < 8; ++t) {
        if (t < 7) OUT_STAGE(cur ^ 1, (t+1)*64);
#pragma unroll
        for (int kk = 0; kk < 2; ++kk) {
            bf16x8_t af[2], bfr[4];
#pragma unroll
            for (int x = 0; x < 2; ++x)
                af[x]  = *reinterpret_cast<const bf16x8_t*>(&As[cur][swz(wr*32 + x*16 + l15, kk*4 + lhi)]);
#pragma unroll
            for (int x = 0; x < 4; ++x)
                bfr[x] = *reinterpret_cast<const bf16x8_t*>(&Bs[cur][swz(wc*64 + x*16 + l15, kk*4 + lhi)]);
            __builtin_amdgcn_s_setprio(1);
#pragma unroll
            for (int mi = 0; mi < 2; ++mi)
#pragma unroll
                for (int nj = 0; nj < 4; ++nj)
                    acc[mi][nj] = __builtin_amdgcn_mfma_f32_16x16x32_bf16(af[mi], bfr[nj], acc[mi][nj], 0, 0, 0);
            __builtin_amdgcn_s_setprio(0);
        }
        if (t < 7) {
            asm volatile("s_waitcnt vmcnt(0)" ::: "memory");
            __syncthreads();
            cur ^= 1;
        }
    }
#undef OUT_STAGE

#pragma unroll
    for (int mi = 0; mi < 2; ++mi) {
#pragma unroll
        for (int nj = 0; nj < 4; ++nj) {
            const int gn = n0 + wc*64 + nj*16 + l15;
            const float bi = bias[gn];
#pragma unroll
            for (int i = 0; i < 4; ++i) {
                const int gm = m0 + wr*32 + mi*16 + lhi*4 + i;
                out[(size_t)gm*512 + gn] = acc[mi][nj][i] + bi;
            }
        }
    }
}

extern "C" void kernel_launch(void* const* d_in, const int* in_sizes, int n_in,
                              void* d_out, int out_size, void* d_ws, size_t ws_size,
                              hipStream_t stream) {
    (void)in_sizes; (void)n_in; (void)out_size; (void)ws_size;
    // setup_inputs order: V, K, Q, M, wx_w, wx_b, wo_w, wo_b  (V,K unused by reference)
    const float* Qin = (const float*)d_in[2];
    const int*   Mm  = (const int*)d_in[3];
    const float* wxw = (const float*)d_in[4];
    const float* wxb = (const float*)d_in[5];
    const float* wow = (const float*)d_in[6];
    const float* wob = (const float*)d_in[7];
    float* out = (float*)d_out;

    char* ws = (char*)d_ws;
    const size_t SZ_A  = (size_t)24576*512*2;   // Q bf16 / attn-out bf16 (reused)
    const size_t SZ_WX = (size_t)1536*512*2;
    const size_t SZ_WO = (size_t)512*512*2;
    const size_t SZ_H  = (size_t)48*8*512*64*2; // per q/k/vT buffer

    unsigned short* Abf  = (unsigned short*)(ws);
    unsigned short* Wxb  = (unsigned short*)(ws + SZ_A);
    unsigned short* Wob  = (unsigned short*)(ws + SZ_A + SZ_WX);
    unsigned short* qb   = (unsigned short*)(ws + SZ_A + SZ_WX + SZ_WO);
    unsigned short* kbuf = (unsigned short*)(ws + SZ_A + SZ_WX + SZ_WO + SZ_H);
    unsigned short* vT   = (unsigned short*)(ws + SZ_A + SZ_WX + SZ_WO + 2*SZ_H);
    unsigned short* attn = Abf;  // reuse: GEMM1 is done with Abf before attention writes

    const int nAll = (24576*512 + 1536*512 + 512*512) / 4;   // float4 elements
    cvt_all<<<(nAll + 255) / 256, 256, 0, stream>>>(Qin, wxw, wow, Abf, Wxb, Wob);

    gemm_qkv<<<2304, 512, 0, stream>>>(Abf, Wxb, wxb, qb, kbuf, vT);
    attn_kernel<<<768, 512, 0, stream>>>(qb, kbuf, vT, Mm, attn);
    gemm_out<<<768, 512, 0, stream>>>(attn, Wob, wob, out);
}